// Round 1
// baseline (629.322 us; speedup 1.0000x reference)
//
#include <hip/hip_runtime.h>
#include <hip/hip_bf16.h>

typedef float  f32x4  __attribute__((ext_vector_type(4)));
typedef __bf16 bf16x8 __attribute__((ext_vector_type(8)));

#define Bz 4
#define Tz 2048
#define Cz 2048
#define Hh 16
#define Dd 128
#define Mm 8192   // B*T

__device__ __forceinline__ void gload_lds16(const __bf16* g, __bf16* l) {
  __builtin_amdgcn_global_load_lds(
      (const __attribute__((address_space(1))) void*)g,
      (__attribute__((address_space(3))) void*)l, 16, 0, 0);
}

// ---------------- f32 -> bf16 convert (vectorized) ----------------
__global__ __launch_bounds__(256)
void cvt_bf16(const float* __restrict__ in, __bf16* __restrict__ out, int n8) {
  int i = blockIdx.x * 256 + threadIdx.x;
  if (i >= n8) return;
  size_t base = (size_t)i * 8;
  f32x4 a = *(const f32x4*)(in + base);
  f32x4 b = *(const f32x4*)(in + base + 4);
  bf16x8 o;
  o[0]=(__bf16)a[0]; o[1]=(__bf16)a[1]; o[2]=(__bf16)a[2]; o[3]=(__bf16)a[3];
  o[4]=(__bf16)b[0]; o[5]=(__bf16)b[1]; o[6]=(__bf16)b[2]; o[7]=(__bf16)b[3];
  *(bf16x8*)(out + base) = o;
}

// ---------------- GEMM: C = A @ W^T + bias ----------------
// A [M][K] bf16 row-major, W [N][K] bf16 row-major (torch Linear weight).
// MODE 0: out bf16 scattered to [B*H][T][D], value = (acc+bias)*scale
// MODE 1: out f32 [M][N], value = acc + bias
template<int MODE>
__global__ __launch_bounds__(256, 2)
void gemm_bt(const __bf16* __restrict__ A, const __bf16* __restrict__ W,
             const float* __restrict__ bias, void* __restrict__ Out,
             int K, float scale)
{
  __shared__ __bf16 As[128 * 64];
  __shared__ __bf16 Bs[128 * 64];

  const int tid  = threadIdx.x;
  const int lane = tid & 63;
  const int wave = tid >> 6;
  const int wm = wave >> 1, wn = wave & 1;
  const int g  = lane >> 4;
  const int lr = lane & 15;
  const int row0 = blockIdx.x * 128;
  const int col0 = blockIdx.y * 128;

  const int srow = lane >> 3;   // 0..7 within 8-row stripe
  const int sblk = lane & 7;    // 16B block within row

  f32x4 acc[4][4] = {};

  for (int kt = 0; kt < K; kt += 64) {
    __syncthreads();
    #pragma unroll
    for (int p = 0; p < 4; ++p) {
      const int rb = p * 32 + wave * 8;
      const int r  = rb + srow;
      const int cb = sblk ^ (r & 7);   // pre-swizzled global source (linear LDS dest)
      gload_lds16(A + (size_t)(row0 + r) * K + kt + cb * 8, As + rb * 64);
      gload_lds16(W + (size_t)(col0 + r) * K + kt + cb * 8, Bs + rb * 64);
    }
    __syncthreads();
    #pragma unroll
    for (int kk = 0; kk < 2; ++kk) {
      bf16x8 af[4], bfr[4];
      #pragma unroll
      for (int i = 0; i < 4; ++i) {
        const int ar = wm * 64 + i * 16 + lr;
        af[i]  = *(const bf16x8*)(As + ar * 64 + ((((kk<<2)|g) ^ (ar & 7)) << 3));
        const int br = wn * 64 + i * 16 + lr;
        bfr[i] = *(const bf16x8*)(Bs + br * 64 + ((((kk<<2)|g) ^ (br & 7)) << 3));
      }
      #pragma unroll
      for (int i = 0; i < 4; ++i)
        #pragma unroll
        for (int j = 0; j < 4; ++j)
          acc[i][j] = __builtin_amdgcn_mfma_f32_16x16x32_bf16(af[i], bfr[j], acc[i][j], 0, 0, 0);
    }
  }

  #pragma unroll
  for (int j = 0; j < 4; ++j) {
    const int col = col0 + wn * 64 + j * 16 + lr;
    const float bv = bias[col];
    #pragma unroll
    for (int i = 0; i < 4; ++i) {
      #pragma unroll
      for (int r = 0; r < 4; ++r) {
        const int row = row0 + wm * 64 + i * 16 + g * 4 + r;
        const float v = acc[i][j][r] + bv;
        if (MODE == 0) {
          const int b = row >> 11, t = row & (Tz - 1);
          const int h = col >> 7,  d = col & (Dd - 1);
          ((__bf16*)Out)[((size_t)(b * Hh + h) * Tz + t) * Dd + d] = (__bf16)(v * scale);
        } else {
          ((float*)Out)[(size_t)row * Cz + col] = v;
        }
      }
    }
  }
}

// ---------------- causal flash attention ----------------
// Q,K,V: [B*H][T][D] bf16 (Q pre-scaled by 1/sqrt(D)).  O: [B*T][C] bf16.
__global__ __launch_bounds__(256, 2)
void attn_fwd(const __bf16* __restrict__ Q, const __bf16* __restrict__ Kg,
              const __bf16* __restrict__ Vg, __bf16* __restrict__ O)
{
  __shared__ __bf16 Ks[64 * 136];     // [kv][d], pad +8
  __shared__ __bf16 Vs[128 * 72];     // [d][kv], pad +8, kv-block XOR swizzled by (d>>3)&7
  __shared__ __bf16 Ps[4][32 * 72];   // per-wave P tile [32 q][64 kv], pad +8

  const int tid  = threadIdx.x;
  const int lane = tid & 63;
  const int wave = tid >> 6;
  const int g  = lane >> 4;
  const int lr = lane & 15;
  const int pair = blockIdx.y;        // b*H + h
  const int qt   = blockIdx.x;
  const int qw0  = qt * 128 + wave * 32;

  const __bf16* Qp = Q  + (size_t)pair * Tz * Dd;
  const __bf16* Kp = Kg + (size_t)pair * Tz * Dd;
  const __bf16* Vp = Vg + (size_t)pair * Tz * Dd;

  // Q fragments in registers (rows qw0..qw0+31)
  bf16x8 qf[2][4];
  #pragma unroll
  for (int im = 0; im < 2; ++im)
    #pragma unroll
    for (int ks = 0; ks < 4; ++ks)
      qf[im][ks] = *(const bf16x8*)(Qp + (size_t)(qw0 + im*16 + lr) * Dd + ks*32 + g*8);

  f32x4 oacc[2][8] = {};
  float mrow[2][4], lsum[2][4];
  #pragma unroll
  for (int im = 0; im < 2; ++im)
    #pragma unroll
    for (int r = 0; r < 4; ++r) { mrow[im][r] = -1e30f; lsum[im][r] = 0.f; }

  const int ntiles = 2 * qt + 2;
  for (int kt = 0; kt < ntiles; ++kt) {
    const int kv0 = kt * 64;
    __syncthreads();
    // stage K (row-major) and V (transposed + swizzled)
    #pragma unroll
    for (int p = 0; p < 4; ++p) {
      const int e = p * 256 + tid;
      const int r = e >> 4;             // kv 0..63
      const int c = (e & 15) * 8;       // d base
      *(bf16x8*)(Ks + r * 136 + c) = *(const bf16x8*)(Kp + (size_t)(kv0 + r) * Dd + c);
      bf16x8 vv = *(const bf16x8*)(Vp + (size_t)(kv0 + r) * Dd + c);
      const int kvb = r >> 3, kvl = r & 7;
      #pragma unroll
      for (int j = 0; j < 8; ++j) {
        const int d = c + j;
        Vs[d * 72 + ((kvb ^ ((d >> 3) & 7)) << 3) + kvl] = vv[j];
      }
    }
    __syncthreads();

    if (kv0 <= qw0 + 31) {
      // ---- S = Q K^T ----
      f32x4 sacc[2][4] = {};
      #pragma unroll
      for (int ks = 0; ks < 4; ++ks) {
        bf16x8 kf[4];
        #pragma unroll
        for (int in = 0; in < 4; ++in)
          kf[in] = *(const bf16x8*)(Ks + (in*16 + lr) * 136 + ks*32 + g*8);
        #pragma unroll
        for (int im = 0; im < 2; ++im)
          #pragma unroll
          for (int in = 0; in < 4; ++in)
            sacc[im][in] = __builtin_amdgcn_mfma_f32_16x16x32_bf16(qf[im][ks], kf[in], sacc[im][in], 0, 0, 0);
      }
      // ---- causal mask (diagonal tiles only) ----
      if (kv0 + 63 > qw0) {
        #pragma unroll
        for (int im = 0; im < 2; ++im)
          #pragma unroll
          for (int in = 0; in < 4; ++in)
            #pragma unroll
            for (int r = 0; r < 4; ++r) {
              const int qrow = qw0 + im*16 + g*4 + r;
              const int kcol = kv0 + in*16 + lr;
              if (kcol > qrow) sacc[im][in][r] = -3e38f;
            }
      }
      // ---- online softmax ----
      #pragma unroll
      for (int im = 0; im < 2; ++im) {
        float mx[4], corr[4];
        #pragma unroll
        for (int r = 0; r < 4; ++r) {
          float m = fmaxf(fmaxf(sacc[im][0][r], sacc[im][1][r]),
                          fmaxf(sacc[im][2][r], sacc[im][3][r]));
          #pragma unroll
          for (int off = 1; off < 16; off <<= 1)
            m = fmaxf(m, __shfl_xor(m, off));
          const float mn = fmaxf(mrow[im][r], m);
          corr[r] = __expf(mrow[im][r] - mn);
          mrow[im][r] = mn;
          mx[r] = mn;
        }
        float rs[4] = {0.f, 0.f, 0.f, 0.f};
        #pragma unroll
        for (int in = 0; in < 4; ++in) {
          #pragma unroll
          for (int r = 0; r < 4; ++r) {
            const float pv = __expf(sacc[im][in][r] - mx[r]);
            rs[r] += pv;
            Ps[wave][(im*16 + g*4 + r) * 72 + in*16 + lr] = (__bf16)pv;
          }
        }
        #pragma unroll
        for (int r = 0; r < 4; ++r) {
          float s = rs[r];
          #pragma unroll
          for (int off = 1; off < 16; off <<= 1)
            s += __shfl_xor(s, off);
          lsum[im][r] = lsum[im][r] * corr[r] + s;
          #pragma unroll
          for (int dn = 0; dn < 8; ++dn)
            oacc[im][dn][r] *= corr[r];
        }
      }
      // ---- O += P V ----
      #pragma unroll
      for (int kk = 0; kk < 2; ++kk) {
        bf16x8 pa[2];
        #pragma unroll
        for (int im = 0; im < 2; ++im)
          pa[im] = *(const bf16x8*)(&Ps[wave][(im*16 + lr) * 72 + kk*32 + g*8]);
        #pragma unroll
        for (int dn = 0; dn < 8; ++dn) {
          const int d = dn*16 + lr;
          bf16x8 vb = *(const bf16x8*)(Vs + d * 72 + (((((kk<<2)|g)) ^ ((d>>3) & 7)) << 3));
          #pragma unroll
          for (int im = 0; im < 2; ++im)
            oacc[im][dn] = __builtin_amdgcn_mfma_f32_16x16x32_bf16(pa[im], vb, oacc[im][dn], 0, 0, 0);
        }
      }
    }
  }

  // ---- epilogue: O[b*T+q][h*D+d] = oacc / lsum ----
  const int b = pair >> 4, h = pair & 15;
  #pragma unroll
  for (int im = 0; im < 2; ++im)
    #pragma unroll
    for (int dn = 0; dn < 8; ++dn)
      #pragma unroll
      for (int r = 0; r < 4; ++r) {
        const int qrow = qw0 + im*16 + g*4 + r;
        const float v = oacc[im][dn][r] / lsum[im][r];
        O[((size_t)(b * Tz + qrow)) * Cz + h * Dd + dn*16 + lr] = (__bf16)v;
      }
}

// ---------------- host launcher ----------------
extern "C" void kernel_launch(void* const* d_in, const int* in_sizes, int n_in,
                              void* d_out, int out_size, void* d_ws, size_t ws_size,
                              hipStream_t stream) {
  const float* x  = (const float*)d_in[0];
  const float* wq = (const float*)d_in[1];
  const float* bq = (const float*)d_in[2];
  const float* wk = (const float*)d_in[3];
  const float* bk = (const float*)d_in[4];
  const float* wv = (const float*)d_in[5];
  const float* bv = (const float*)d_in[6];
  const float* wo = (const float*)d_in[7];
  const float* bo = (const float*)d_in[8];
  float* out = (float*)d_out;

  char* w = (char*)d_ws;
  __bf16* xb   = (__bf16*)w; w += (size_t)Mm * Cz * 2;   // x bf16; reused as attn-out later
  __bf16* wbuf = (__bf16*)w; w += (size_t)Cz * Cz * 2;   // current weight bf16
  __bf16* qb   = (__bf16*)w; w += (size_t)Mm * Cz * 2;
  __bf16* kb   = (__bf16*)w; w += (size_t)Mm * Cz * 2;
  __bf16* vbuf = (__bf16*)w; w += (size_t)Mm * Cz * 2;
  if (ws_size < (size_t)(w - (char*)d_ws)) return;  // workspace too small: fail loudly

  const int nx8 = Mm * Cz / 8;   // 2,097,152
  const int nw8 = Cz * Cz / 8;   //   524,288
  dim3 ggrid(Mm / 128, Cz / 128);
  const float qscale = 0.08838834764831845f;  // 1/sqrt(128)

  cvt_bf16<<<nx8 / 256, 256, 0, stream>>>(x, xb, nx8);

  cvt_bf16<<<nw8 / 256, 256, 0, stream>>>(wq, wbuf, nw8);
  gemm_bt<0><<<ggrid, 256, 0, stream>>>(xb, wbuf, bq, qb, Cz, qscale);

  cvt_bf16<<<nw8 / 256, 256, 0, stream>>>(wk, wbuf, nw8);
  gemm_bt<0><<<ggrid, 256, 0, stream>>>(xb, wbuf, bk, kb, Cz, 1.0f);

  cvt_bf16<<<nw8 / 256, 256, 0, stream>>>(wv, wbuf, nw8);
  gemm_bt<0><<<ggrid, 256, 0, stream>>>(xb, wbuf, bv, vbuf, Cz, 1.0f);

  // attention writes its output over xb (x no longer needed)
  __bf16* ob = xb;
  attn_fwd<<<dim3(Tz / 128, Bz * Hh), 256, 0, stream>>>(qb, kb, vbuf, ob);

  cvt_bf16<<<nw8 / 256, 256, 0, stream>>>(wo, wbuf, nw8);
  gemm_bt<1><<<ggrid, 256, 0, stream>>>(ob, wbuf, bo, out, Cz, 1.0f);
}

// Round 2
// 465.081 us; speedup vs baseline: 1.3531x; 1.3531x over previous
//
#include <hip/hip_runtime.h>
#include <hip/hip_bf16.h>

typedef float  f32x4  __attribute__((ext_vector_type(4)));
typedef __bf16 bf16x8 __attribute__((ext_vector_type(8)));
typedef __bf16 bf16x4 __attribute__((ext_vector_type(4)));

#define Bz 4
#define Tz 2048
#define Cz 2048
#define Hh 16
#define Dd 128
#define Mm 8192   // B*T

__device__ __forceinline__ void gload_lds16(const __bf16* g, __bf16* l) {
  __builtin_amdgcn_global_load_lds(
      (const __attribute__((address_space(1))) void*)g,
      (__attribute__((address_space(3))) void*)l, 16, 0, 0);
}

// ---------------- f32 -> bf16 convert (vectorized) ----------------
__global__ __launch_bounds__(256)
void cvt_bf16(const float* __restrict__ in, __bf16* __restrict__ out, int n8) {
  int i = blockIdx.x * 256 + threadIdx.x;
  if (i >= n8) return;
  size_t base = (size_t)i * 8;
  f32x4 a = *(const f32x4*)(in + base);
  f32x4 b = *(const f32x4*)(in + base + 4);
  bf16x8 o;
  o[0]=(__bf16)a[0]; o[1]=(__bf16)a[1]; o[2]=(__bf16)a[2]; o[3]=(__bf16)a[3];
  o[4]=(__bf16)b[0]; o[5]=(__bf16)b[1]; o[6]=(__bf16)b[2]; o[7]=(__bf16)b[3];
  *(bf16x8*)(out + base) = o;
}

// ---------------- GEMM: C = A @ W^T + bias ----------------
// A [M][K] bf16 row-major, W [N][K] bf16 row-major (torch Linear weight).
// MODE 0: out bf16 scattered to [B*H][T][D], value = (acc+bias)*scale
// MODE 1: out f32 [M][N], value = acc + bias
// MODE 2: out bf16 scattered to [B*H][D][T] (transposed, for V)
template<int MODE>
__global__ __launch_bounds__(256, 2)
void gemm_bt(const __bf16* __restrict__ A, const __bf16* __restrict__ W,
             const float* __restrict__ bias, void* __restrict__ Out,
             int K, float scale)
{
  __shared__ __bf16 As[128 * 64];
  __shared__ __bf16 Bs[128 * 64];

  const int tid  = threadIdx.x;
  const int lane = tid & 63;
  const int wave = tid >> 6;
  const int wm = wave >> 1, wn = wave & 1;
  const int g  = lane >> 4;
  const int lr = lane & 15;
  const int row0 = blockIdx.x * 128;
  const int col0 = blockIdx.y * 128;

  const int srow = lane >> 3;   // 0..7 within 8-row stripe
  const int sblk = lane & 7;    // 16B block within row

  f32x4 acc[4][4] = {};

  for (int kt = 0; kt < K; kt += 64) {
    __syncthreads();
    #pragma unroll
    for (int p = 0; p < 4; ++p) {
      const int rb = p * 32 + wave * 8;
      const int r  = rb + srow;
      const int cb = sblk ^ (r & 7);   // pre-swizzled global source (linear LDS dest)
      gload_lds16(A + (size_t)(row0 + r) * K + kt + cb * 8, As + rb * 64);
      gload_lds16(W + (size_t)(col0 + r) * K + kt + cb * 8, Bs + rb * 64);
    }
    __syncthreads();
    #pragma unroll
    for (int kk = 0; kk < 2; ++kk) {
      bf16x8 af[4], bfr[4];
      #pragma unroll
      for (int i = 0; i < 4; ++i) {
        const int ar = wm * 64 + i * 16 + lr;
        af[i]  = *(const bf16x8*)(As + ar * 64 + ((((kk<<2)|g) ^ (ar & 7)) << 3));
        const int br = wn * 64 + i * 16 + lr;
        bfr[i] = *(const bf16x8*)(Bs + br * 64 + ((((kk<<2)|g) ^ (br & 7)) << 3));
      }
      #pragma unroll
      for (int i = 0; i < 4; ++i)
        #pragma unroll
        for (int j = 0; j < 4; ++j)
          acc[i][j] = __builtin_amdgcn_mfma_f32_16x16x32_bf16(af[i], bfr[j], acc[i][j], 0, 0, 0);
    }
  }

  #pragma unroll
  for (int j = 0; j < 4; ++j) {
    const int col = col0 + wn * 64 + j * 16 + lr;
    const float bv = bias[col];
    #pragma unroll
    for (int i = 0; i < 4; ++i) {
      if (MODE == 2) {
        // V^T layout: Vt[(pair*D + d)*T + t]; 4 consecutive t per lane -> 8B store
        const int row = row0 + wm * 64 + i * 16 + g * 4;   // first of 4 rows
        const int b = row >> 11, t = row & (Tz - 1);
        const int h = col >> 7,  d = col & (Dd - 1);
        bf16x4 v4;
        #pragma unroll
        for (int r = 0; r < 4; ++r) v4[r] = (__bf16)(acc[i][j][r] + bv);
        *(bf16x4*)((__bf16*)Out + ((size_t)(b * Hh + h) * Dd + d) * Tz + t) = v4;
      } else {
        #pragma unroll
        for (int r = 0; r < 4; ++r) {
          const int row = row0 + wm * 64 + i * 16 + g * 4 + r;
          const float v = acc[i][j][r] + bv;
          if (MODE == 0) {
            const int b = row >> 11, t = row & (Tz - 1);
            const int h = col >> 7,  d = col & (Dd - 1);
            ((__bf16*)Out)[((size_t)(b * Hh + h) * Tz + t) * Dd + d] = (__bf16)(v * scale);
          } else {
            ((float*)Out)[(size_t)row * Cz + col] = v;
          }
        }
      }
    }
  }
}

// ---------------- causal flash attention ----------------
// Q,K: [B*H][T][D] bf16 (Q pre-scaled by 1/sqrt(D)). Vt: [B*H][D][T] bf16.
// O: [B*T][C] bf16.
// Block handles q-tiles qtA=blockIdx.x and qtB=15-blockIdx.x sequentially
// (equal total work per block: 34 kv-tile-units).
__global__ __launch_bounds__(256, 2)
void attn_fwd(const __bf16* __restrict__ Q, const __bf16* __restrict__ Kg,
              const __bf16* __restrict__ Vt, __bf16* __restrict__ O)
{
  __shared__ __bf16 Ks[64 * 128];     // [kv][d] linear, 16B-block XOR swizzle by (kv&7)
  __shared__ __bf16 Vs[128 * 64];     // [d][kv] linear, 16B-block XOR swizzle by (d&7)
  __shared__ __bf16 Ps[4][32 * 72];   // per-wave P tile [32 q][64 kv], pad +8

  const int tid  = threadIdx.x;
  const int lane = tid & 63;
  const int wave = tid >> 6;
  const int g  = lane >> 4;
  const int lr = lane & 15;
  const int pair = blockIdx.y;        // b*H + h
  const int b = pair >> 4, h = pair & 15;

  const __bf16* Qp = Q  + (size_t)pair * Tz * Dd;
  const __bf16* Kp = Kg + (size_t)pair * Tz * Dd;
  const __bf16* Vp = Vt + (size_t)pair * Dd * Tz;

  // staging indices (per thread, loop-invariant)
  const int krow[4] = { 0*16 + wave*4 + (lane>>4), 1*16 + wave*4 + (lane>>4),
                        2*16 + wave*4 + (lane>>4), 3*16 + wave*4 + (lane>>4) };
  const int vrow[4] = { 0*32 + wave*8 + (lane>>3), 1*32 + wave*8 + (lane>>3),
                        2*32 + wave*8 + (lane>>3), 3*32 + wave*8 + (lane>>3) };

  #pragma unroll
  for (int pass = 0; pass < 2; ++pass) {
    const int qt  = pass == 0 ? (15 - blockIdx.x) : blockIdx.x;
    const int qw0 = qt * 128 + wave * 32;

    // Q fragments in registers (rows qw0..qw0+31)
    bf16x8 qf[2][4];
    #pragma unroll
    for (int im = 0; im < 2; ++im)
      #pragma unroll
      for (int ks = 0; ks < 4; ++ks)
        qf[im][ks] = *(const bf16x8*)(Qp + (size_t)(qw0 + im*16 + lr) * Dd + ks*32 + g*8);

    f32x4 oacc[2][8] = {};
    float mrow[2][4], lsum[2][4];
    #pragma unroll
    for (int im = 0; im < 2; ++im)
      #pragma unroll
      for (int r = 0; r < 4; ++r) { mrow[im][r] = -1e30f; lsum[im][r] = 0.f; }

    const int ntiles = 2 * qt + 2;
    for (int kt = 0; kt < ntiles; ++kt) {
      const int kv0 = kt * 64;
      __syncthreads();
      // async stage: K tile [64][128] and V^T tile [128][64], swizzled source
      #pragma unroll
      for (int p = 0; p < 4; ++p) {
        const int r  = krow[p];
        const int cb = (lane & 15) ^ (r & 7);
        gload_lds16(Kp + (size_t)(kv0 + r) * Dd + cb * 8, Ks + p * 2048 + wave * 512);
        const int d  = vrow[p];
        const int cv = (lane & 7) ^ (d & 7);
        gload_lds16(Vp + (size_t)d * Tz + kv0 + cv * 8, Vs + p * 2048 + wave * 512);
      }
      __syncthreads();

      if (kv0 <= qw0 + 31) {
        // ---- S = Q K^T ----
        f32x4 sacc[2][4] = {};
        #pragma unroll
        for (int ks = 0; ks < 4; ++ks) {
          bf16x8 kf[4];
          #pragma unroll
          for (int in = 0; in < 4; ++in) {
            const int r = in*16 + lr;
            kf[in] = *(const bf16x8*)(Ks + r * 128 + ((((ks<<2)|g) ^ (r & 7)) << 3));
          }
          #pragma unroll
          for (int im = 0; im < 2; ++im)
            #pragma unroll
            for (int in = 0; in < 4; ++in)
              sacc[im][in] = __builtin_amdgcn_mfma_f32_16x16x32_bf16(qf[im][ks], kf[in], sacc[im][in], 0, 0, 0);
        }
        // ---- causal mask (diagonal tiles only) ----
        if (kv0 + 63 > qw0) {
          #pragma unroll
          for (int im = 0; im < 2; ++im)
            #pragma unroll
            for (int in = 0; in < 4; ++in)
              #pragma unroll
              for (int r = 0; r < 4; ++r) {
                const int qrow = qw0 + im*16 + g*4 + r;
                const int kcol = kv0 + in*16 + lr;
                if (kcol > qrow) sacc[im][in][r] = -3e38f;
              }
        }
        // ---- online softmax ----
        #pragma unroll
        for (int im = 0; im < 2; ++im) {
          float mx[4], corr[4];
          #pragma unroll
          for (int r = 0; r < 4; ++r) {
            float m = fmaxf(fmaxf(sacc[im][0][r], sacc[im][1][r]),
                            fmaxf(sacc[im][2][r], sacc[im][3][r]));
            #pragma unroll
            for (int off = 1; off < 16; off <<= 1)
              m = fmaxf(m, __shfl_xor(m, off));
            const float mn = fmaxf(mrow[im][r], m);
            corr[r] = __expf(mrow[im][r] - mn);
            mrow[im][r] = mn;
            mx[r] = mn;
          }
          float rs[4] = {0.f, 0.f, 0.f, 0.f};
          #pragma unroll
          for (int in = 0; in < 4; ++in) {
            #pragma unroll
            for (int r = 0; r < 4; ++r) {
              const float pv = __expf(sacc[im][in][r] - mx[r]);
              rs[r] += pv;
              Ps[wave][(im*16 + g*4 + r) * 72 + in*16 + lr] = (__bf16)pv;
            }
          }
          #pragma unroll
          for (int r = 0; r < 4; ++r) {
            float s = rs[r];
            #pragma unroll
            for (int off = 1; off < 16; off <<= 1)
              s += __shfl_xor(s, off);
            lsum[im][r] = lsum[im][r] * corr[r] + s;
            #pragma unroll
            for (int dn = 0; dn < 8; ++dn)
              oacc[im][dn][r] *= corr[r];
          }
        }
        // ---- O += P V ----
        #pragma unroll
        for (int kk = 0; kk < 2; ++kk) {
          bf16x8 pa[2];
          #pragma unroll
          for (int im = 0; im < 2; ++im)
            pa[im] = *(const bf16x8*)(&Ps[wave][(im*16 + lr) * 72 + kk*32 + g*8]);
          #pragma unroll
          for (int dn = 0; dn < 8; ++dn) {
            const int d = dn*16 + lr;
            bf16x8 vb = *(const bf16x8*)(Vs + d * 64 + ((((kk<<2)|g) ^ (d & 7)) << 3));
            #pragma unroll
            for (int im = 0; im < 2; ++im)
              oacc[im][dn] = __builtin_amdgcn_mfma_f32_16x16x32_bf16(pa[im], vb, oacc[im][dn], 0, 0, 0);
          }
        }
      }
    }

    // ---- epilogue: O[b*T+q][h*D+d] = oacc / lsum ----
    #pragma unroll
    for (int im = 0; im < 2; ++im)
      #pragma unroll
      for (int dn = 0; dn < 8; ++dn)
        #pragma unroll
        for (int r = 0; r < 4; ++r) {
          const int qrow = qw0 + im*16 + g*4 + r;
          const float v = oacc[im][dn][r] / lsum[im][r];
          O[((size_t)(b * Tz + qrow)) * Cz + h * Dd + dn*16 + lr] = (__bf16)v;
        }
  }
}

// ---------------- host launcher ----------------
extern "C" void kernel_launch(void* const* d_in, const int* in_sizes, int n_in,
                              void* d_out, int out_size, void* d_ws, size_t ws_size,
                              hipStream_t stream) {
  const float* x  = (const float*)d_in[0];
  const float* wq = (const float*)d_in[1];
  const float* bq = (const float*)d_in[2];
  const float* wk = (const float*)d_in[3];
  const float* bk = (const float*)d_in[4];
  const float* wv = (const float*)d_in[5];
  const float* bv = (const float*)d_in[6];
  const float* wo = (const float*)d_in[7];
  const float* bo = (const float*)d_in[8];
  float* out = (float*)d_out;

  char* w = (char*)d_ws;
  __bf16* xb   = (__bf16*)w; w += (size_t)Mm * Cz * 2;   // x bf16; reused as attn-out later
  __bf16* wbuf = (__bf16*)w; w += (size_t)Cz * Cz * 2;   // current weight bf16
  __bf16* qb   = (__bf16*)w; w += (size_t)Mm * Cz * 2;
  __bf16* kb   = (__bf16*)w; w += (size_t)Mm * Cz * 2;
  __bf16* vbuf = (__bf16*)w; w += (size_t)Mm * Cz * 2;
  if (ws_size < (size_t)(w - (char*)d_ws)) return;  // workspace too small: fail loudly

  const int nx8 = Mm * Cz / 8;   // 2,097,152
  const int nw8 = Cz * Cz / 8;   //   524,288
  dim3 ggrid(Mm / 128, Cz / 128);
  const float qscale = 0.08838834764831845f;  // 1/sqrt(128)

  cvt_bf16<<<nx8 / 256, 256, 0, stream>>>(x, xb, nx8);

  cvt_bf16<<<nw8 / 256, 256, 0, stream>>>(wq, wbuf, nw8);
  gemm_bt<0><<<ggrid, 256, 0, stream>>>(xb, wbuf, bq, qb, Cz, qscale);

  cvt_bf16<<<nw8 / 256, 256, 0, stream>>>(wk, wbuf, nw8);
  gemm_bt<0><<<ggrid, 256, 0, stream>>>(xb, wbuf, bk, kb, Cz, 1.0f);

  cvt_bf16<<<nw8 / 256, 256, 0, stream>>>(wv, wbuf, nw8);
  gemm_bt<2><<<ggrid, 256, 0, stream>>>(xb, wbuf, bv, vbuf, Cz, 1.0f);  // writes V^T

  // attention writes its output over xb (x no longer needed)
  __bf16* ob = xb;
  attn_fwd<<<dim3(8, Bz * Hh), 256, 0, stream>>>(qb, kb, vbuf, ob);

  cvt_bf16<<<nw8 / 256, 256, 0, stream>>>(wo, wbuf, nw8);
  gemm_bt<1><<<ggrid, 256, 0, stream>>>(ob, wbuf, bo, out, Cz, 1.0f);
}

// Round 3
// 453.963 us; speedup vs baseline: 1.3863x; 1.0245x over previous
//
#include <hip/hip_runtime.h>
#include <hip/hip_bf16.h>

typedef float  f32x4  __attribute__((ext_vector_type(4)));
typedef __bf16 bf16x8 __attribute__((ext_vector_type(8)));
typedef __bf16 bf16x4 __attribute__((ext_vector_type(4)));

#define Bz 4
#define Tz 2048
#define Cz 2048
#define Hh 16
#define Dd 128
#define Mm 8192   // B*T

__device__ __forceinline__ void gload_lds16(const __bf16* g, __bf16* l) {
  __builtin_amdgcn_global_load_lds(
      (const __attribute__((address_space(1))) void*)g,
      (__attribute__((address_space(3))) void*)l, 16, 0, 0);
}

// ---------------- f32 -> bf16 convert (vectorized) ----------------
__global__ __launch_bounds__(256)
void cvt_bf16(const float* __restrict__ in, __bf16* __restrict__ out, int n8) {
  int i = blockIdx.x * 256 + threadIdx.x;
  if (i >= n8) return;
  size_t base = (size_t)i * 8;
  f32x4 a = *(const f32x4*)(in + base);
  f32x4 b = *(const f32x4*)(in + base + 4);
  bf16x8 o;
  o[0]=(__bf16)a[0]; o[1]=(__bf16)a[1]; o[2]=(__bf16)a[2]; o[3]=(__bf16)a[3];
  o[4]=(__bf16)b[0]; o[5]=(__bf16)b[1]; o[6]=(__bf16)b[2]; o[7]=(__bf16)b[3];
  *(bf16x8*)(out + base) = o;
}

// ---------------- GEMM: C = A @ W^T + bias ----------------
// A [M][K] bf16 row-major, W [N][K] bf16 row-major (torch Linear weight).
// MODE 0: out bf16 scattered to [B*H][T][D], value = (acc+bias)*scale
// MODE 1: out f32 [M][N], value = acc + bias
// MODE 2: out bf16 scattered to [B*H][D][T] (transposed, for V)
template<int MODE>
__global__ __launch_bounds__(256, 2)
void gemm_bt(const __bf16* __restrict__ A, const __bf16* __restrict__ W,
             const float* __restrict__ bias, void* __restrict__ Out,
             int K, float scale)
{
  __shared__ __bf16 As[128 * 64];
  __shared__ __bf16 Bs[128 * 64];

  const int tid  = threadIdx.x;
  const int lane = tid & 63;
  const int wave = tid >> 6;
  const int wm = wave >> 1, wn = wave & 1;
  const int g  = lane >> 4;
  const int lr = lane & 15;
  const int row0 = blockIdx.x * 128;
  const int col0 = blockIdx.y * 128;

  const int srow = lane >> 3;   // 0..7 within 8-row stripe
  const int sblk = lane & 7;    // 16B block within row

  f32x4 acc[4][4] = {};

  for (int kt = 0; kt < K; kt += 64) {
    __syncthreads();
    #pragma unroll
    for (int p = 0; p < 4; ++p) {
      const int rb = p * 32 + wave * 8;
      const int r  = rb + srow;
      const int cb = sblk ^ (r & 7);   // pre-swizzled global source (linear LDS dest)
      gload_lds16(A + (size_t)(row0 + r) * K + kt + cb * 8, As + rb * 64);
      gload_lds16(W + (size_t)(col0 + r) * K + kt + cb * 8, Bs + rb * 64);
    }
    __syncthreads();
    #pragma unroll
    for (int kk = 0; kk < 2; ++kk) {
      bf16x8 af[4], bfr[4];
      #pragma unroll
      for (int i = 0; i < 4; ++i) {
        const int ar = wm * 64 + i * 16 + lr;
        af[i]  = *(const bf16x8*)(As + ar * 64 + ((((kk<<2)|g) ^ (ar & 7)) << 3));
        const int br = wn * 64 + i * 16 + lr;
        bfr[i] = *(const bf16x8*)(Bs + br * 64 + ((((kk<<2)|g) ^ (br & 7)) << 3));
      }
      #pragma unroll
      for (int i = 0; i < 4; ++i)
        #pragma unroll
        for (int j = 0; j < 4; ++j)
          acc[i][j] = __builtin_amdgcn_mfma_f32_16x16x32_bf16(af[i], bfr[j], acc[i][j], 0, 0, 0);
    }
  }

  #pragma unroll
  for (int j = 0; j < 4; ++j) {
    const int col = col0 + wn * 64 + j * 16 + lr;
    const float bv = bias[col];
    #pragma unroll
    for (int i = 0; i < 4; ++i) {
      if (MODE == 2) {
        // V^T layout: Vt[(pair*D + d)*T + t]; 4 consecutive t per lane -> 8B store
        const int row = row0 + wm * 64 + i * 16 + g * 4;   // first of 4 rows
        const int b = row >> 11, t = row & (Tz - 1);
        const int h = col >> 7,  d = col & (Dd - 1);
        bf16x4 v4;
        #pragma unroll
        for (int r = 0; r < 4; ++r) v4[r] = (__bf16)(acc[i][j][r] + bv);
        *(bf16x4*)((__bf16*)Out + ((size_t)(b * Hh + h) * Dd + d) * Tz + t) = v4;
      } else {
        #pragma unroll
        for (int r = 0; r < 4; ++r) {
          const int row = row0 + wm * 64 + i * 16 + g * 4 + r;
          const float v = acc[i][j][r] + bv;
          if (MODE == 0) {
            const int b = row >> 11, t = row & (Tz - 1);
            const int h = col >> 7,  d = col & (Dd - 1);
            ((__bf16*)Out)[((size_t)(b * Hh + h) * Tz + t) * Dd + d] = (__bf16)(v * scale);
          } else {
            ((float*)Out)[(size_t)row * Cz + col] = v;
          }
        }
      }
    }
  }
}

// ---------------- causal flash attention ----------------
// Q,K: [B*H][T][D] bf16 (Q pre-scaled by log2(e)/sqrt(D)). Vt: [B*H][D][T] bf16.
// O: [B*T][C] bf16. Softmax computed in log2 domain (exp2).
// Block handles q-tiles 15-blockIdx.x and blockIdx.x sequentially (34 tile-units each).
// K/V double-buffered: issue stage(t+1) -> compute(t) -> barrier (one barrier/tile).
__global__ __launch_bounds__(256, 2)
void attn_fwd(const __bf16* __restrict__ Q, const __bf16* __restrict__ Kg,
              const __bf16* __restrict__ Vt, __bf16* __restrict__ O)
{
  __shared__ __bf16 Ks[2][64 * 128];   // [kv][d], 16B-block XOR swizzle by (kv&7)
  __shared__ __bf16 Vs[2][128 * 64];   // [d][kv], 16B-block XOR swizzle by (d&7)
  __shared__ __bf16 Ps[4][32 * 64];    // per-wave P, 16B-block XOR swizzle by (q&7)
  // total: 32K + 32K + 16K = 80 KB -> 2 blocks/CU

  const int tid  = threadIdx.x;
  const int lane = tid & 63;
  const int wave = tid >> 6;
  const int g  = lane >> 4;
  const int lr = lane & 15;
  const int pair = blockIdx.y;        // b*H + h
  const int b = pair >> 4, h = pair & 15;

  const __bf16* Qp = Q  + (size_t)pair * Tz * Dd;
  const __bf16* Kp = Kg + (size_t)pair * Tz * Dd;
  const __bf16* Vp = Vt + (size_t)pair * Dd * Tz;

  #define STAGE_KV(kv0_, buf_)                                                  \
    {                                                                           \
      const int kv0s = (kv0_);                                                  \
      _Pragma("unroll")                                                         \
      for (int p = 0; p < 4; ++p) {                                             \
        const int r  = p * 16 + wave * 4 + (lane >> 4);                         \
        const int cb = (lane & 15) ^ (r & 7);                                   \
        gload_lds16(Kp + (size_t)(kv0s + r) * Dd + cb * 8,                      \
                    &Ks[buf_][p * 2048 + wave * 512]);                          \
        const int d  = p * 32 + wave * 8 + (lane >> 3);                         \
        const int cv = (lane & 7) ^ (d & 7);                                    \
        gload_lds16(Vp + (size_t)d * Tz + kv0s + cv * 8,                        \
                    &Vs[buf_][p * 2048 + wave * 512]);                          \
      }                                                                         \
    }

  for (int pass = 0; pass < 2; ++pass) {
    const int qt  = pass == 0 ? (15 - (int)blockIdx.x) : (int)blockIdx.x;
    const int qw0 = qt * 128 + wave * 32;

    // Q fragments in registers (rows qw0..qw0+31)
    bf16x8 qf[2][4];
    #pragma unroll
    for (int im = 0; im < 2; ++im)
      #pragma unroll
      for (int ks = 0; ks < 4; ++ks)
        qf[im][ks] = *(const bf16x8*)(Qp + (size_t)(qw0 + im*16 + lr) * Dd + ks*32 + g*8);

    f32x4 oacc[2][8] = {};
    float mrow[2][4], lsum[2][4];
    #pragma unroll
    for (int im = 0; im < 2; ++im)
      #pragma unroll
      for (int r = 0; r < 4; ++r) { mrow[im][r] = -1e30f; lsum[im][r] = 0.f; }

    const int ntiles = 2 * qt + 2;

    STAGE_KV(0, 0);
    __syncthreads();   // drains prologue loads (compiler emits vmcnt(0) before barrier)

    for (int kt = 0; kt < ntiles; ++kt) {
      const int cur = kt & 1;
      const int kv0 = kt * 64;
      if (kt + 1 < ntiles) STAGE_KV((kt + 1) * 64, cur ^ 1);

      if (kv0 <= qw0 + 31) {
        // ---- S = Q K^T (log2-domain logits) ----
        f32x4 sacc[2][4] = {};
        __builtin_amdgcn_s_setprio(1);
        #pragma unroll
        for (int ks = 0; ks < 4; ++ks) {
          bf16x8 kf[4];
          #pragma unroll
          for (int in = 0; in < 4; ++in) {
            const int r = in*16 + lr;
            kf[in] = *(const bf16x8*)(&Ks[cur][r * 128 + ((((ks<<2)|g) ^ (r & 7)) << 3)]);
          }
          #pragma unroll
          for (int im = 0; im < 2; ++im)
            #pragma unroll
            for (int in = 0; in < 4; ++in)
              sacc[im][in] = __builtin_amdgcn_mfma_f32_16x16x32_bf16(qf[im][ks], kf[in], sacc[im][in], 0, 0, 0);
        }
        __builtin_amdgcn_s_setprio(0);
        // ---- causal mask (diagonal tiles only) ----
        if (kv0 + 63 > qw0) {
          #pragma unroll
          for (int im = 0; im < 2; ++im)
            #pragma unroll
            for (int in = 0; in < 4; ++in)
              #pragma unroll
              for (int r = 0; r < 4; ++r) {
                const int qrow = qw0 + im*16 + g*4 + r;
                const int kcol = kv0 + in*16 + lr;
                if (kcol > qrow) sacc[im][in][r] = -3e38f;
              }
        }
        // ---- online softmax (exp2 domain, defer-max THR = 8 nats = 11.54 log2) ----
        #pragma unroll
        for (int im = 0; im < 2; ++im) {
          float pmax[4];
          #pragma unroll
          for (int r = 0; r < 4; ++r) {
            float m = fmaxf(fmaxf(sacc[im][0][r], sacc[im][1][r]),
                            fmaxf(sacc[im][2][r], sacc[im][3][r]));
            #pragma unroll
            for (int off = 1; off < 16; off <<= 1)
              m = fmaxf(m, __shfl_xor(m, off));
            pmax[r] = m;
          }
          bool need = false;
          #pragma unroll
          for (int r = 0; r < 4; ++r) need |= (pmax[r] > mrow[im][r] + 11.54f);
          if (__any(need)) {
            #pragma unroll
            for (int r = 0; r < 4; ++r) {
              const bool  up = pmax[r] > mrow[im][r] + 11.54f;
              const float mn = up ? pmax[r] : mrow[im][r];
              const float corr = exp2f(mrow[im][r] - mn);   // ==1 when kept
              mrow[im][r] = mn;
              lsum[im][r] *= corr;
              #pragma unroll
              for (int dn = 0; dn < 8; ++dn)
                oacc[im][dn][r] *= corr;
            }
          }
          float rs[4] = {0.f, 0.f, 0.f, 0.f};
          #pragma unroll
          for (int in = 0; in < 4; ++in) {
            #pragma unroll
            for (int r = 0; r < 4; ++r) {
              const float pv = __builtin_amdgcn_exp2f(sacc[im][in][r] - mrow[im][r]);
              rs[r] += pv;
              const int row = im*16 + g*4 + r;
              const int col = in*16 + lr;
              Ps[wave][row * 64 + ((((col >> 3) ^ (row & 7)) << 3) | (col & 7))] = (__bf16)pv;
            }
          }
          #pragma unroll
          for (int r = 0; r < 4; ++r) {
            float s = rs[r];
            #pragma unroll
            for (int off = 1; off < 16; off <<= 1)
              s += __shfl_xor(s, off);
            lsum[im][r] += s;
          }
        }
        // ---- O += P V ----
        __builtin_amdgcn_s_setprio(1);
        #pragma unroll
        for (int kk = 0; kk < 2; ++kk) {
          bf16x8 pa[2];
          #pragma unroll
          for (int im = 0; im < 2; ++im) {
            const int row = im*16 + lr;
            pa[im] = *(const bf16x8*)(&Ps[wave][row * 64 + ((((kk<<2)|g) ^ (row & 7)) << 3)]);
          }
          #pragma unroll
          for (int dn = 0; dn < 8; ++dn) {
            const int d = dn*16 + lr;
            bf16x8 vb = *(const bf16x8*)(&Vs[cur][d * 64 + ((((kk<<2)|g) ^ (d & 7)) << 3)]);
            #pragma unroll
            for (int im = 0; im < 2; ++im)
              oacc[im][dn] = __builtin_amdgcn_mfma_f32_16x16x32_bf16(pa[im], vb, oacc[im][dn], 0, 0, 0);
          }
        }
        __builtin_amdgcn_s_setprio(0);
      }
      __syncthreads();   // publishes buf[cur^1] stages; protects buf[cur] reuse
    }

    // ---- epilogue: O[b*T+q][h*D+d] = oacc / lsum ----
    #pragma unroll
    for (int im = 0; im < 2; ++im)
      #pragma unroll
      for (int dn = 0; dn < 8; ++dn)
        #pragma unroll
        for (int r = 0; r < 4; ++r) {
          const int qrow = qw0 + im*16 + g*4 + r;
          const float v = oacc[im][dn][r] / lsum[im][r];
          O[((size_t)(b * Tz + qrow)) * Cz + h * Dd + dn*16 + lr] = (__bf16)v;
        }
  }
  #undef STAGE_KV
}

// ---------------- host launcher ----------------
extern "C" void kernel_launch(void* const* d_in, const int* in_sizes, int n_in,
                              void* d_out, int out_size, void* d_ws, size_t ws_size,
                              hipStream_t stream) {
  const float* x  = (const float*)d_in[0];
  const float* wq = (const float*)d_in[1];
  const float* bq = (const float*)d_in[2];
  const float* wk = (const float*)d_in[3];
  const float* bk = (const float*)d_in[4];
  const float* wv = (const float*)d_in[5];
  const float* bv = (const float*)d_in[6];
  const float* wo = (const float*)d_in[7];
  const float* bo = (const float*)d_in[8];
  float* out = (float*)d_out;

  char* w = (char*)d_ws;
  __bf16* xb   = (__bf16*)w; w += (size_t)Mm * Cz * 2;   // x bf16; reused as attn-out later
  __bf16* wbuf = (__bf16*)w; w += (size_t)Cz * Cz * 2;   // current weight bf16
  __bf16* qb   = (__bf16*)w; w += (size_t)Mm * Cz * 2;
  __bf16* kb   = (__bf16*)w; w += (size_t)Mm * Cz * 2;
  __bf16* vbuf = (__bf16*)w; w += (size_t)Mm * Cz * 2;
  if (ws_size < (size_t)(w - (char*)d_ws)) return;  // workspace too small: fail loudly

  const int nx8 = Mm * Cz / 8;   // 2,097,152
  const int nw8 = Cz * Cz / 8;   //   524,288
  dim3 ggrid(Mm / 128, Cz / 128);
  // 1/sqrt(128) * log2(e): softmax runs in exp2 domain
  const float qscale = 0.12752551286084110f;

  cvt_bf16<<<nx8 / 256, 256, 0, stream>>>(x, xb, nx8);

  cvt_bf16<<<nw8 / 256, 256, 0, stream>>>(wq, wbuf, nw8);
  gemm_bt<0><<<ggrid, 256, 0, stream>>>(xb, wbuf, bq, qb, Cz, qscale);

  cvt_bf16<<<nw8 / 256, 256, 0, stream>>>(wk, wbuf, nw8);
  gemm_bt<0><<<ggrid, 256, 0, stream>>>(xb, wbuf, bk, kb, Cz, 1.0f);

  cvt_bf16<<<nw8 / 256, 256, 0, stream>>>(wv, wbuf, nw8);
  gemm_bt<2><<<ggrid, 256, 0, stream>>>(xb, wbuf, bv, vbuf, Cz, 1.0f);  // writes V^T

  // attention writes its output over xb (x no longer needed)
  __bf16* ob = xb;
  attn_fwd<<<dim3(8, Bz * Hh), 256, 0, stream>>>(qb, kb, vbuf, ob);

  cvt_bf16<<<nw8 / 256, 256, 0, stream>>>(wo, wbuf, nw8);
  gemm_bt<1><<<ggrid, 256, 0, stream>>>(ob, wbuf, bo, out, Cz, 1.0f);
}

// Round 5
// 412.275 us; speedup vs baseline: 1.5265x; 1.1011x over previous
//
#include <hip/hip_runtime.h>
#include <hip/hip_bf16.h>

typedef float  f32x4  __attribute__((ext_vector_type(4)));
typedef __bf16 bf16x8 __attribute__((ext_vector_type(8)));
typedef __bf16 bf16x4 __attribute__((ext_vector_type(4)));

#define Bz 4
#define Tz 2048
#define Cz 2048
#define Hh 16
#define Dd 128
#define Mm 8192   // B*T

__device__ __forceinline__ void gload_lds16(const __bf16* g, __bf16* l) {
  __builtin_amdgcn_global_load_lds(
      (const __attribute__((address_space(1))) void*)g,
      (__attribute__((address_space(3))) void*)l, 16, 0, 0);
}

// ---------------- f32 -> bf16 convert (vectorized) ----------------
__global__ __launch_bounds__(256)
void cvt_bf16(const float* __restrict__ in, __bf16* __restrict__ out, int n8) {
  int i = blockIdx.x * 256 + threadIdx.x;
  if (i >= n8) return;
  size_t base = (size_t)i * 8;
  f32x4 a = *(const f32x4*)(in + base);
  f32x4 b = *(const f32x4*)(in + base + 4);
  bf16x8 o;
  o[0]=(__bf16)a[0]; o[1]=(__bf16)a[1]; o[2]=(__bf16)a[2]; o[3]=(__bf16)a[3];
  o[4]=(__bf16)b[0]; o[5]=(__bf16)b[1]; o[6]=(__bf16)b[2]; o[7]=(__bf16)b[3];
  *(bf16x8*)(out + base) = o;
}

// ---------------- GEMM: C = A @ W^T + bias ----------------
// A [M][K] bf16 row-major, W [N][K] bf16 row-major (torch Linear weight).
// MODE 0: out bf16 scattered to [B*H][T][D], value = (acc+bias)*scale
// MODE 1: out f32 [M][N], value = acc + bias
// MODE 2: out bf16 scattered to [B*H][D][T] (transposed, for V)
template<int MODE>
__global__ __launch_bounds__(256, 2)
void gemm_bt(const __bf16* __restrict__ A, const __bf16* __restrict__ W,
             const float* __restrict__ bias, void* __restrict__ Out,
             int K, float scale)
{
  __shared__ __bf16 As[128 * 64];
  __shared__ __bf16 Bs[128 * 64];

  const int tid  = threadIdx.x;
  const int lane = tid & 63;
  const int wave = tid >> 6;
  const int wm = wave >> 1, wn = wave & 1;
  const int g  = lane >> 4;
  const int lr = lane & 15;
  const int row0 = blockIdx.x * 128;
  const int col0 = blockIdx.y * 128;

  const int srow = lane >> 3;   // 0..7 within 8-row stripe
  const int sblk = lane & 7;    // 16B block within row

  f32x4 acc[4][4] = {};

  for (int kt = 0; kt < K; kt += 64) {
    __syncthreads();
    #pragma unroll
    for (int p = 0; p < 4; ++p) {
      const int rb = p * 32 + wave * 8;
      const int r  = rb + srow;
      const int cb = sblk ^ (r & 7);   // pre-swizzled global source (linear LDS dest)
      gload_lds16(A + (size_t)(row0 + r) * K + kt + cb * 8, As + rb * 64);
      gload_lds16(W + (size_t)(col0 + r) * K + kt + cb * 8, Bs + rb * 64);
    }
    __syncthreads();
    #pragma unroll
    for (int kk = 0; kk < 2; ++kk) {
      bf16x8 af[4], bfr[4];
      #pragma unroll
      for (int i = 0; i < 4; ++i) {
        const int ar = wm * 64 + i * 16 + lr;
        af[i]  = *(const bf16x8*)(As + ar * 64 + ((((kk<<2)|g) ^ (ar & 7)) << 3));
        const int br = wn * 64 + i * 16 + lr;
        bfr[i] = *(const bf16x8*)(Bs + br * 64 + ((((kk<<2)|g) ^ (br & 7)) << 3));
      }
      #pragma unroll
      for (int i = 0; i < 4; ++i)
        #pragma unroll
        for (int j = 0; j < 4; ++j)
          acc[i][j] = __builtin_amdgcn_mfma_f32_16x16x32_bf16(af[i], bfr[j], acc[i][j], 0, 0, 0);
    }
  }

  #pragma unroll
  for (int j = 0; j < 4; ++j) {
    const int col = col0 + wn * 64 + j * 16 + lr;
    const float bv = bias[col];
    #pragma unroll
    for (int i = 0; i < 4; ++i) {
      if (MODE == 2) {
        // V^T layout: Vt[(pair*D + d)*T + t]; 4 consecutive t per lane -> 8B store
        const int row = row0 + wm * 64 + i * 16 + g * 4;   // first of 4 rows
        const int b = row >> 11, t = row & (Tz - 1);
        const int h = col >> 7,  d = col & (Dd - 1);
        bf16x4 v4;
        #pragma unroll
        for (int r = 0; r < 4; ++r) v4[r] = (__bf16)(acc[i][j][r] + bv);
        *(bf16x4*)((__bf16*)Out + ((size_t)(b * Hh + h) * Dd + d) * Tz + t) = v4;
      } else {
        #pragma unroll
        for (int r = 0; r < 4; ++r) {
          const int row = row0 + wm * 64 + i * 16 + g * 4 + r;
          const float v = acc[i][j][r] + bv;
          if (MODE == 0) {
            const int b = row >> 11, t = row & (Tz - 1);
            const int h = col >> 7,  d = col & (Dd - 1);
            ((__bf16*)Out)[((size_t)(b * Hh + h) * Tz + t) * Dd + d] = (__bf16)(v * scale);
          } else {
            ((float*)Out)[(size_t)row * Cz + col] = v;
          }
        }
      }
    }
  }
}

// ---------------- causal flash attention (swapped QK^T) ----------------
// Q,K: [B*H][T][D] bf16 (Q pre-scaled by log2(e)/sqrt(D)). Vt: [B*H][D][T] bf16.
// O: [B*T][C] bf16. Softmax in exp2 domain, fully in-register per q-row:
// S^T = mfma(K,Q) puts q on the lane column (q = lr), 16 kv values in-lane.
__global__ __launch_bounds__(256, 2)
void attn_fwd(const __bf16* __restrict__ Q, const __bf16* __restrict__ Kg,
              const __bf16* __restrict__ Vt, __bf16* __restrict__ O)
{
  __shared__ __bf16 Ks[2][64 * 128];   // [kv][d], 16B-block XOR swizzle by (kv&7)
  __shared__ __bf16 Vs[2][128 * 64];   // [d][kv], 16B-block XOR swizzle by (d&7)
  __shared__ __bf16 Ps[4][32 * 64];    // per-wave P [32 q][64 kv], 8B-quad XOR swizzle by (q&3)<<2
  // total: 32K + 32K + 16K = 80 KB -> 2 blocks/CU

  const int tid  = threadIdx.x;
  const int lane = tid & 63;
  const int wave = tid >> 6;
  const int g  = lane >> 4;
  const int lr = lane & 15;
  const int pair = blockIdx.y;        // b*H + h
  const int b = pair >> 4, h = pair & 15;

  const __bf16* Qp = Q  + (size_t)pair * Tz * Dd;
  const __bf16* Kp = Kg + (size_t)pair * Tz * Dd;
  const __bf16* Vp = Vt + (size_t)pair * Dd * Tz;

  #define STAGE_KV(kv0_, buf_)                                                  \
    {                                                                           \
      const int kv0s = (kv0_);                                                  \
      _Pragma("unroll")                                                         \
      for (int p = 0; p < 4; ++p) {                                             \
        const int r  = p * 16 + wave * 4 + (lane >> 4);                         \
        const int cb = (lane & 15) ^ (r & 7);                                   \
        gload_lds16(Kp + (size_t)(kv0s + r) * Dd + cb * 8,                      \
                    &Ks[buf_][p * 2048 + wave * 512]);                          \
        const int d  = p * 32 + wave * 8 + (lane >> 3);                         \
        const int cv = (lane & 7) ^ (d & 7);                                    \
        gload_lds16(Vp + (size_t)d * Tz + kv0s + cv * 8,                        \
                    &Vs[buf_][p * 2048 + wave * 512]);                          \
      }                                                                         \
    }

  for (int pass = 0; pass < 2; ++pass) {
    const int qt  = pass == 0 ? (15 - (int)blockIdx.x) : (int)blockIdx.x;
    const int qw0 = qt * 128 + wave * 32;

    // Q fragments in registers (rows qw0..qw0+31)
    bf16x8 qf[2][4];
    #pragma unroll
    for (int im = 0; im < 2; ++im)
      #pragma unroll
      for (int ks = 0; ks < 4; ++ks)
        qf[im][ks] = *(const bf16x8*)(Qp + (size_t)(qw0 + im*16 + lr) * Dd + ks*32 + g*8);

    f32x4 oacc[2][8] = {};          // O[q = g*4+r][d = dn*16+lr]
    float mrow[2], lsum[2];         // per-lane holder for q-row = qw0 + im*16 + lr
    mrow[0] = mrow[1] = -1e30f;
    lsum[0] = lsum[1] = 0.f;

    const int ntiles = 2 * qt + 2;

    STAGE_KV(0, 0);
    __syncthreads();   // drains prologue loads

    for (int kt = 0; kt < ntiles; ++kt) {
      const int cur = kt & 1;
      const int kv0 = kt * 64;
      if (kt + 1 < ntiles) STAGE_KV((kt + 1) * 64, cur ^ 1);

      if (kv0 <= qw0 + 31) {
        // ---- S^T = K Q^T : sacc[im][in], lane holds q = qw0+im*16+lr,
        //      kv = kv0 + in*16 + g*4 + r ----
        f32x4 sacc[2][4] = {};
        __builtin_amdgcn_s_setprio(1);
        #pragma unroll
        for (int ks = 0; ks < 4; ++ks) {
          bf16x8 kf[4];
          #pragma unroll
          for (int in = 0; in < 4; ++in) {
            const int r = in*16 + lr;
            kf[in] = *(const bf16x8*)(&Ks[cur][r * 128 + ((((ks<<2)|g) ^ (r & 7)) << 3)]);
          }
          #pragma unroll
          for (int im = 0; im < 2; ++im)
            #pragma unroll
            for (int in = 0; in < 4; ++in)
              sacc[im][in] = __builtin_amdgcn_mfma_f32_16x16x32_bf16(kf[in], qf[im][ks], sacc[im][in], 0, 0, 0);
        }
        __builtin_amdgcn_s_setprio(0);

        // ---- causal mask (diagonal tiles only) ----
        if (kv0 + 63 > qw0) {
          #pragma unroll
          for (int im = 0; im < 2; ++im) {
            const int q = qw0 + im*16 + lr;
            #pragma unroll
            for (int in = 0; in < 4; ++in)
              #pragma unroll
              for (int r = 0; r < 4; ++r) {
                const int kv = kv0 + in*16 + g*4 + r;
                if (kv > q) sacc[im][in][r] = -3e38f;
              }
          }
        }

        // ---- online softmax, in-register (exp2 domain, defer-max 8 nats) ----
        #pragma unroll
        for (int im = 0; im < 2; ++im) {
          float m = fmaxf(fmaxf(sacc[im][0][0], sacc[im][0][1]),
                          fmaxf(sacc[im][0][2], sacc[im][0][3]));
          #pragma unroll
          for (int in = 1; in < 4; ++in)
            m = fmaxf(m, fmaxf(fmaxf(sacc[im][in][0], sacc[im][in][1]),
                               fmaxf(sacc[im][in][2], sacc[im][in][3])));
          m = fmaxf(m, __shfl_xor(m, 16));
          m = fmaxf(m, __shfl_xor(m, 32));

          const bool need = m > mrow[im] + 11.54f;
          if (__any(need)) {
            const float mn   = need ? m : mrow[im];
            const float corr = __builtin_amdgcn_exp2f(mrow[im] - mn);
            mrow[im] = mn;
            lsum[im] *= corr;
            // oacc rows are q = g*4+r; corr lives in lanes lr = q.
            const int sb = 20 * g;             // srcLane = 16g + (4g+r)
            const float c0 = __shfl(corr, sb + 0);
            const float c1 = __shfl(corr, sb + 1);
            const float c2 = __shfl(corr, sb + 2);
            const float c3 = __shfl(corr, sb + 3);
            #pragma unroll
            for (int dn = 0; dn < 8; ++dn) {
              oacc[im][dn][0] *= c0; oacc[im][dn][1] *= c1;
              oacc[im][dn][2] *= c2; oacc[im][dn][3] *= c3;
            }
          }

          float rs = 0.f;
          const int prow = im*16 + lr;
          #pragma unroll
          for (int in = 0; in < 4; ++in) {
            const float p0 = __builtin_amdgcn_exp2f(sacc[im][in][0] - mrow[im]);
            const float p1 = __builtin_amdgcn_exp2f(sacc[im][in][1] - mrow[im]);
            const float p2 = __builtin_amdgcn_exp2f(sacc[im][in][2] - mrow[im]);
            const float p3 = __builtin_amdgcn_exp2f(sacc[im][in][3] - mrow[im]);
            rs += (p0 + p1) + (p2 + p3);
            bf16x4 q4;
            q4[0] = (__bf16)p0; q4[1] = (__bf16)p1;
            q4[2] = (__bf16)p2; q4[3] = (__bf16)p3;
            const int bs = (in*4 + g) ^ ((prow & 3) << 2);   // 8B-quad swizzle
            *(bf16x4*)(&Ps[wave][prow * 64 + bs * 4]) = q4;
          }
          rs += __shfl_xor(rs, 16);
          rs += __shfl_xor(rs, 32);
          lsum[im] += rs;
        }

        // ---- O += P V ----
        __builtin_amdgcn_s_setprio(1);
        #pragma unroll
        for (int kk = 0; kk < 2; ++kk) {
          bf16x8 pa[2];
          #pragma unroll
          for (int im = 0; im < 2; ++im) {
            const int prow = im*16 + lr;
            const int bs = (kk*8 + 2*g) ^ ((prow & 3) << 2);
            pa[im] = *(const bf16x8*)(&Ps[wave][prow * 64 + bs * 4]);
          }
          #pragma unroll
          for (int dn = 0; dn < 8; ++dn) {
            const int d = dn*16 + lr;
            bf16x8 vb = *(const bf16x8*)(&Vs[cur][d * 64 + ((((kk<<2)|g) ^ (d & 7)) << 3)]);
            #pragma unroll
            for (int im = 0; im < 2; ++im)
              oacc[im][dn] = __builtin_amdgcn_mfma_f32_16x16x32_bf16(pa[im], vb, oacc[im][dn], 0, 0, 0);
          }
        }
        __builtin_amdgcn_s_setprio(0);
      }
      __syncthreads();   // publishes buf[cur^1] stages; protects buf[cur] reuse
    }

    // ---- epilogue: O[b*T+q][h*D+d] = oacc / lsum ----
    #pragma unroll
    for (int im = 0; im < 2; ++im) {
      const float inv = 1.0f / lsum[im];      // holder lanes: q = lr
      const int sb = 20 * g;
      const float i0 = __shfl(inv, sb + 0);
      const float i1 = __shfl(inv, sb + 1);
      const float i2 = __shfl(inv, sb + 2);
      const float i3 = __shfl(inv, sb + 3);
      #pragma unroll
      for (int dn = 0; dn < 8; ++dn) {
        const int qrow = qw0 + im*16 + g*4;
        const int d    = h * Dd + dn*16 + lr;
        O[((size_t)(b * Tz + qrow + 0)) * Cz + d] = (__bf16)(oacc[im][dn][0] * i0);
        O[((size_t)(b * Tz + qrow + 1)) * Cz + d] = (__bf16)(oacc[im][dn][1] * i1);
        O[((size_t)(b * Tz + qrow + 2)) * Cz + d] = (__bf16)(oacc[im][dn][2] * i2);
        O[((size_t)(b * Tz + qrow + 3)) * Cz + d] = (__bf16)(oacc[im][dn][3] * i3);
      }
    }
  }
  #undef STAGE_KV
}

// ---------------- host launcher ----------------
extern "C" void kernel_launch(void* const* d_in, const int* in_sizes, int n_in,
                              void* d_out, int out_size, void* d_ws, size_t ws_size,
                              hipStream_t stream) {
  const float* x  = (const float*)d_in[0];
  const float* wq = (const float*)d_in[1];
  const float* bq = (const float*)d_in[2];
  const float* wk = (const float*)d_in[3];
  const float* bk = (const float*)d_in[4];
  const float* wv = (const float*)d_in[5];
  const float* bv = (const float*)d_in[6];
  const float* wo = (const float*)d_in[7];
  const float* bo = (const float*)d_in[8];
  float* out = (float*)d_out;

  char* w = (char*)d_ws;
  __bf16* xb   = (__bf16*)w; w += (size_t)Mm * Cz * 2;   // x bf16; reused as attn-out later
  __bf16* wbuf = (__bf16*)w; w += (size_t)Cz * Cz * 2;   // current weight bf16
  __bf16* qb   = (__bf16*)w; w += (size_t)Mm * Cz * 2;
  __bf16* kb   = (__bf16*)w; w += (size_t)Mm * Cz * 2;
  __bf16* vbuf = (__bf16*)w; w += (size_t)Mm * Cz * 2;
  if (ws_size < (size_t)(w - (char*)d_ws)) return;  // workspace too small: fail loudly

  const int nx8 = Mm * Cz / 8;   // 2,097,152
  const int nw8 = Cz * Cz / 8;   //   524,288
  dim3 ggrid(Mm / 128, Cz / 128);
  // 1/sqrt(128) * log2(e): softmax runs in exp2 domain
  const float qscale = 0.12752551286084110f;

  cvt_bf16<<<nx8 / 256, 256, 0, stream>>>(x, xb, nx8);

  cvt_bf16<<<nw8 / 256, 256, 0, stream>>>(wq, wbuf, nw8);
  gemm_bt<0><<<ggrid, 256, 0, stream>>>(xb, wbuf, bq, qb, Cz, qscale);

  cvt_bf16<<<nw8 / 256, 256, 0, stream>>>(wk, wbuf, nw8);
  gemm_bt<0><<<ggrid, 256, 0, stream>>>(xb, wbuf, bk, kb, Cz, 1.0f);

  cvt_bf16<<<nw8 / 256, 256, 0, stream>>>(wv, wbuf, nw8);
  gemm_bt<2><<<ggrid, 256, 0, stream>>>(xb, wbuf, bv, vbuf, Cz, 1.0f);  // writes V^T

  // attention writes its output over xb (x no longer needed)
  __bf16* ob = xb;
  attn_fwd<<<dim3(8, Bz * Hh), 256, 0, stream>>>(qb, kb, vbuf, ob);

  cvt_bf16<<<nw8 / 256, 256, 0, stream>>>(wo, wbuf, nw8);
  gemm_bt<1><<<ggrid, 256, 0, stream>>>(ob, wbuf, bo, out, Cz, 1.0f);
}